// Round 1
// baseline (356.484 us; speedup 1.0000x reference)
//
#include <hip/hip_runtime.h>

#define B_   2
#define N_   2048
#define DIM_ 1024
#define H_   16
#define DH_  64
#define M_   (B_*N_)      // 4096 rows of x
#define QKVN (3*DIM_)     // 3072

typedef __attribute__((ext_vector_type(8))) short  short8;
typedef __attribute__((ext_vector_type(4))) float  floatx4;

// ---------- helpers ----------
__device__ inline unsigned short f2b(float f) {
  union { float f; unsigned u; } v; v.f = f;
  unsigned r = v.u + 0x7fffu + ((v.u >> 16) & 1u);   // round-to-nearest-even
  return (unsigned short)(r >> 16);
}

__device__ inline floatx4 mfma16(short8 a, short8 b, floatx4 c) {
  return __builtin_amdgcn_mfma_f32_16x16x32_bf16(a, b, c, 0, 0, 0);
}

// XOR swizzle for [64][64] bf16 LDS tiles (128B rows): permutes 16B chunks
// within a row by row&7 — kills the same-bank column conflict (G4).
// Returns ushort element index.
__device__ inline int swz(int row, int byteoff) {
  return row * 64 + (((byteoff) ^ ((row & 7) << 4)) >> 1);
}

// ---------- tiny prep kernels ----------
__global__ void cast_x_kernel(const float* __restrict__ x, unsigned short* __restrict__ xb) {
  int i = blockIdx.x * 256 + threadIdx.x;          // exactly M_*DIM_/4 threads
  float4 v = ((const float4*)x)[i];
  ushort4 o;
  o.x = f2b(v.x); o.y = f2b(v.y); o.z = f2b(v.z); o.w = f2b(v.w);
  ((ushort4*)xb)[i] = o;
}

__global__ void trig_kernel(const float* __restrict__ pos,
                            float* __restrict__ c, float* __restrict__ s) {
  int i = blockIdx.x * 256 + threadIdx.x;          // exactly N_*DH_ threads
  float a = pos[i];
  c[i] = cosf(a);
  s[i] = sinf(a);
}

// W [1024][1024] fp32 -> WT [1024][1024] bf16 with WT[n][k] = W[k][n]
__global__ void transpose_w_kernel(const float* __restrict__ W0, const float* __restrict__ W1,
                                   const float* __restrict__ W2, const float* __restrict__ W3,
                                   unsigned short* __restrict__ T0, unsigned short* __restrict__ T1,
                                   unsigned short* __restrict__ T2, unsigned short* __restrict__ T3) {
  int z = blockIdx.z;
  const float* W = (z == 0) ? W0 : (z == 1) ? W1 : (z == 2) ? W2 : W3;
  unsigned short* T = (z == 0) ? T0 : (z == 1) ? T1 : (z == 2) ? T2 : T3;
  __shared__ float tile[32][33];
  int x = threadIdx.x, y = threadIdx.y;            // blockDim (32,8)
  int bx = blockIdx.x * 32, by = blockIdx.y * 32;
  #pragma unroll
  for (int i = 0; i < 32; i += 8)
    tile[y + i][x] = W[(size_t)(by + y + i) * 1024 + bx + x];
  __syncthreads();
  #pragma unroll
  for (int i = 0; i < 32; i += 8)
    T[(size_t)(bx + y + i) * 1024 + by + x] = f2b(tile[x][y + i]);
}

// ---------- GEMM: C[M][N] (+bias) = A_bf16[M][K] * BT_bf16[N][K] ----------
// 128x128 tile, BK=32, 256 threads = 4 waves in 2x2, each wave 64x64 = 4x4 frags.
__global__ __launch_bounds__(256) void gemm_bt_kernel(
    const unsigned short* __restrict__ A, const unsigned short* __restrict__ BT,
    float* __restrict__ C, const float* __restrict__ bias, int M, int N, int K)
{
  __shared__ __align__(16) unsigned short As[128 * 32];
  __shared__ __align__(16) unsigned short Bs[128 * 32];
  int t = threadIdx.x;
  int lane = t & 63, wave = t >> 6;
  int wr = (wave >> 1) * 64, wc = (wave & 1) * 64;

  const unsigned short* Ab = A  + (size_t)(blockIdx.y * 128) * K;
  const unsigned short* Bb = BT + (size_t)(blockIdx.x * 128) * K;
  int srow = t >> 2;            // 0..63
  int scol = (t & 3) * 8;       // element offset in the 32-wide K slice

  floatx4 acc[4][4];
  #pragma unroll
  for (int i = 0; i < 4; ++i)
    #pragma unroll
    for (int j = 0; j < 4; ++j)
      acc[i][j] = (floatx4){0.f, 0.f, 0.f, 0.f};

  const unsigned short* Ap0 = Ab + (size_t)srow * K + scol;
  const unsigned short* Ap1 = Ab + (size_t)(64 + srow) * K + scol;
  const unsigned short* Bp0 = Bb + (size_t)srow * K + scol;
  const unsigned short* Bp1 = Bb + (size_t)(64 + srow) * K + scol;

  int nk = K >> 5;
  int4 ra0 = *(const int4*)(Ap0), ra1 = *(const int4*)(Ap1);
  int4 rb0 = *(const int4*)(Bp0), rb1 = *(const int4*)(Bp1);

  for (int kt = 0;;) {
    *(int4*)&As[srow * 32 + scol]        = ra0;
    *(int4*)&As[(64 + srow) * 32 + scol] = ra1;
    *(int4*)&Bs[srow * 32 + scol]        = rb0;
    *(int4*)&Bs[(64 + srow) * 32 + scol] = rb1;
    __syncthreads();
    if (kt + 1 < nk) {                    // prefetch next K-slice (in flight over MFMA)
      int ko = (kt + 1) * 32;
      ra0 = *(const int4*)(Ap0 + ko); ra1 = *(const int4*)(Ap1 + ko);
      rb0 = *(const int4*)(Bp0 + ko); rb1 = *(const int4*)(Bp1 + ko);
    }
    short8 af[4], bf[4];
    #pragma unroll
    for (int fi = 0; fi < 4; ++fi)
      af[fi] = *(const short8*)&As[(wr + fi * 16 + (lane & 15)) * 32 + (lane >> 4) * 8];
    #pragma unroll
    for (int fj = 0; fj < 4; ++fj)
      bf[fj] = *(const short8*)&Bs[(wc + fj * 16 + (lane & 15)) * 32 + (lane >> 4) * 8];
    #pragma unroll
    for (int fi = 0; fi < 4; ++fi)
      #pragma unroll
      for (int fj = 0; fj < 4; ++fj)
        acc[fi][fj] = mfma16(af[fi], bf[fj], acc[fi][fj]);
    if (++kt == nk) break;
    __syncthreads();
  }

  int row0 = blockIdx.y * 128 + wr + (lane >> 4) * 4;
  int col0 = blockIdx.x * 128 + wc + (lane & 15);
  #pragma unroll
  for (int fi = 0; fi < 4; ++fi) {
    #pragma unroll
    for (int fj = 0; fj < 4; ++fj) {
      int col = col0 + fj * 16;
      float bv = bias ? bias[col] : 0.f;
      #pragma unroll
      for (int r = 0; r < 4; ++r) {
        int row = row0 + fi * 16 + r;
        C[(size_t)row * N + col] = acc[fi][fj][r] + bv;
      }
    }
  }
}

// ---------- RoPE + head split: qkv_f32[4096][3072] -> q,k,v bf16 [B][H][N][64] ----------
__global__ void rope_kernel(const float* __restrict__ qkv,
                            const float* __restrict__ cT, const float* __restrict__ sT,
                            unsigned short* __restrict__ qb, unsigned short* __restrict__ kb,
                            unsigned short* __restrict__ vb)
{
  int tid = blockIdx.x * 256 + threadIdx.x;   // exactly M_*H_*32 threads
  int d = tid & 31;
  int h = (tid >> 5) & 15;
  int m = tid >> 9;                            // 0..4095  (= b*N_+n)
  int n = m & (N_ - 1);
  const float* rowp = qkv + (size_t)m * QKVN + h * 64 + d;
  float q1 = rowp[0],        q2 = rowp[32];
  float k1 = rowp[1024],     k2 = rowp[1024 + 32];
  float v1 = rowp[2048],     v2 = rowp[2048 + 32];
  float c1 = cT[n * 64 + d], c2 = cT[n * 64 + d + 32];
  float s1 = sT[n * 64 + d], s2 = sT[n * 64 + d + 32];
  const float scale = 0.125f;                  // DH^-0.5
  size_t o = (((size_t)(m >> 11) * H_ + h) * N_ + n) * DH_ + d;
  qb[o]      = f2b((q1 * c1 - q2 * s1) * scale);
  qb[o + 32] = f2b((q2 * c2 + q1 * s2) * scale);
  kb[o]      = f2b(k1 * c1 - k2 * s1);
  kb[o + 32] = f2b(k2 * c2 + k1 * s2);
  vb[o]      = f2b(v1);
  vb[o + 32] = f2b(v2);
}

// ---------- causal flash attention ----------
// block = 256 thr = 4 waves; Q-tile 64 rows (wave w owns rows w*16..+15); KV tile 64.
__global__ __launch_bounds__(256) void attn_kernel(
    const unsigned short* __restrict__ qg, const unsigned short* __restrict__ kg,
    const unsigned short* __restrict__ vg, unsigned short* __restrict__ ctx)
{
  int qt = blockIdx.x & 31;
  int bh = blockIdx.x >> 5;                 // b*H + h
  int q0 = qt * 64;
  int t = threadIdx.x, lane = t & 63, wave = t >> 6;

  __shared__ __align__(16) unsigned short Qs[64 * 64];
  __shared__ __align__(16) unsigned short Ks[64 * 64];
  __shared__ __align__(16) unsigned short Vs[64 * 64];   // stored transposed: [dh][kv]
  __shared__ __align__(16) unsigned short Ps[64 * 64];

  const unsigned short* qp = qg + ((size_t)bh * N_ + q0) * DH_;
  const unsigned short* kp = kg + (size_t)bh * N_ * DH_;
  const unsigned short* vp = vg + (size_t)bh * N_ * DH_;

  { // stage Q (64x64 bf16), swizzled
    int row = t >> 2, bo = (t & 3) * 32;
    const int4* src = (const int4*)(qp + row * 64 + bo / 2);
    int4 a = src[0], b = src[1];
    *(int4*)&Qs[swz(row, bo)]      = a;
    *(int4*)&Qs[swz(row, bo + 16)] = b;
  }
  __syncthreads();
  short8 qf0, qf1;
  { // Q fragments held in registers for the whole KV loop
    int row = wave * 16 + (lane & 15);
    qf0 = *(const short8*)&Qs[swz(row, (lane >> 4) * 16)];
    qf1 = *(const short8*)&Qs[swz(row, 64 + (lane >> 4) * 16)];
  }

  floatx4 o_[4];
  #pragma unroll
  for (int nb = 0; nb < 4; ++nb) o_[nb] = (floatx4){0.f, 0.f, 0.f, 0.f};
  float mr[4], lr[4];
  #pragma unroll
  for (int r = 0; r < 4; ++r) { mr[r] = -1e30f; lr[r] = 0.f; }

  int nt = qt + 1;
  for (int kt = 0; kt < nt; ++kt) {
    int kv0 = kt * 64;
    __syncthreads();                         // prior iter's LDS reads done
    { // stage K
      int row = t >> 2, bo = (t & 3) * 32;
      const int4* src = (const int4*)(kp + (size_t)(kv0 + row) * 64 + bo / 2);
      int4 a = src[0], b = src[1];
      *(int4*)&Ks[swz(row, bo)]      = a;
      *(int4*)&Ks[swz(row, bo + 16)] = b;
    }
    { // stage V transposed
      int r = t >> 2, d0 = (t & 3) * 16;
      const unsigned short* src = vp + (size_t)(kv0 + r) * 64 + d0;
      int4 a = *(const int4*)src, b = *(const int4*)(src + 8);
      __align__(16) unsigned short tmp[16];
      *(int4*)tmp = a; *(int4*)(tmp + 8) = b;
      #pragma unroll
      for (int j = 0; j < 16; ++j)
        Vs[swz(d0 + j, r * 2)] = tmp[j];
    }
    __syncthreads();

    // S = Q K^T  (per wave: 16 q-rows x 64 kv-cols)
    floatx4 s_[4];
    #pragma unroll
    for (int nb = 0; nb < 4; ++nb) s_[nb] = (floatx4){0.f, 0.f, 0.f, 0.f};
    #pragma unroll
    for (int nb = 0; nb < 4; ++nb) {
      int krow = nb * 16 + (lane & 15);
      short8 b0 = *(const short8*)&Ks[swz(krow, (lane >> 4) * 16)];
      short8 b1 = *(const short8*)&Ks[swz(krow, 64 + (lane >> 4) * 16)];
      s_[nb] = mfma16(qf0, b0, s_[nb]);
      s_[nb] = mfma16(qf1, b1, s_[nb]);
    }

    if (kt == qt) { // causal mask (only the diagonal tile needs it)
      #pragma unroll
      for (int nb = 0; nb < 4; ++nb) {
        int col = kv0 + nb * 16 + (lane & 15);
        #pragma unroll
        for (int r = 0; r < 4; ++r) {
          int row = q0 + wave * 16 + (lane >> 4) * 4 + r;
          if (col > row) s_[nb][r] = -1e30f;
        }
      }
    }

    // online softmax (rows live in 16-lane groups, 4 rows/lane via reg r)
    float tm[4];
    #pragma unroll
    for (int r = 0; r < 4; ++r) {
      tm[r] = fmaxf(fmaxf(s_[0][r], s_[1][r]), fmaxf(s_[2][r], s_[3][r]));
      #pragma unroll
      for (int msk = 1; msk < 16; msk <<= 1)
        tm[r] = fmaxf(tm[r], __shfl_xor(tm[r], msk, 64));
    }
    float nm[4], al[4], ps[4];
    #pragma unroll
    for (int r = 0; r < 4; ++r) {
      nm[r] = fmaxf(mr[r], tm[r]);
      al[r] = expf(mr[r] - nm[r]);
      mr[r] = nm[r];
      ps[r] = 0.f;
    }
    int prow = wave * 16 + (lane >> 4) * 4;
    #pragma unroll
    for (int nb = 0; nb < 4; ++nb) {
      int pcol = nb * 16 + (lane & 15);
      #pragma unroll
      for (int r = 0; r < 4; ++r) {
        float p = expf(s_[nb][r] - nm[r]);
        ps[r] += p;
        Ps[swz(prow + r, pcol * 2)] = f2b(p);
      }
    }
    #pragma unroll
    for (int r = 0; r < 4; ++r) {
      #pragma unroll
      for (int msk = 1; msk < 16; msk <<= 1)
        ps[r] += __shfl_xor(ps[r], msk, 64);
      lr[r] = lr[r] * al[r] + ps[r];
    }
    #pragma unroll
    for (int nb = 0; nb < 4; ++nb)
      #pragma unroll
      for (int r = 0; r < 4; ++r)
        o_[nb][r] *= al[r];

    // O += P V   (P from this wave's private Ps rows; V^T in LDS)
    short8 pa0 = *(const short8*)&Ps[swz(wave * 16 + (lane & 15), (lane >> 4) * 16)];
    short8 pa1 = *(const short8*)&Ps[swz(wave * 16 + (lane & 15), 64 + (lane >> 4) * 16)];
    #pragma unroll
    for (int nb = 0; nb < 4; ++nb) {
      int vrow = nb * 16 + (lane & 15);
      short8 v0 = *(const short8*)&Vs[swz(vrow, (lane >> 4) * 16)];
      short8 v1 = *(const short8*)&Vs[swz(vrow, 64 + (lane >> 4) * 16)];
      o_[nb] = mfma16(pa0, v0, o_[nb]);
      o_[nb] = mfma16(pa1, v1, o_[nb]);
    }
  }

  // epilogue: ctx[b][n][h*64+dh] bf16
  int b = bh >> 4, h = bh & 15;
  #pragma unroll
  for (int nb = 0; nb < 4; ++nb) {
    int col = h * 64 + nb * 16 + (lane & 15);
    #pragma unroll
    for (int r = 0; r < 4; ++r) {
      int n = q0 + wave * 16 + (lane >> 4) * 4 + r;
      ctx[((size_t)(b * N_ + n)) * DIM_ + col] = f2b(o_[nb][r] / lr[r]);
    }
  }
}

// ---------- launch ----------
extern "C" void kernel_launch(void* const* d_in, const int* in_sizes, int n_in,
                              void* d_out, int out_size, void* d_ws, size_t ws_size,
                              hipStream_t stream)
{
  const float* x   = (const float*)d_in[0];
  const float* pos = (const float*)d_in[1];
  const float* Wq  = (const float*)d_in[2];
  const float* Wk  = (const float*)d_in[3];
  const float* Wv  = (const float*)d_in[4];
  const float* Wo  = (const float*)d_in[5];
  const float* bo  = (const float*)d_in[6];
  float* out = (float*)d_out;

  char* w = (char*)d_ws;
  size_t off = 0;
  auto alloc = [&](size_t bytes) {
    char* p = w + off;
    off += (bytes + 255) & ~(size_t)255;
    return p;
  };
  unsigned short* xb  = (unsigned short*)alloc((size_t)M_ * DIM_ * 2);        // 8 MB
  unsigned short* WT  = (unsigned short*)alloc((size_t)QKVN * DIM_ * 2);      // 6 MB
  unsigned short* WoT = (unsigned short*)alloc((size_t)DIM_ * DIM_ * 2);      // 2 MB
  float* cT = (float*)alloc((size_t)N_ * DH_ * 4);                            // 0.5 MB
  float* sT = (float*)alloc((size_t)N_ * DH_ * 4);                            // 0.5 MB
  float* qkvf = (float*)alloc((size_t)M_ * QKVN * 4);                         // 48 MB
  unsigned short* qb = (unsigned short*)alloc((size_t)B_ * H_ * N_ * DH_ * 2);// 8 MB
  unsigned short* kb = (unsigned short*)alloc((size_t)B_ * H_ * N_ * DH_ * 2);// 8 MB
  unsigned short* vb = (unsigned short*)alloc((size_t)B_ * H_ * N_ * DH_ * 2);// 8 MB
  unsigned short* ctx = (unsigned short*)qkvf;  // alias: qkv_f32 is dead after rope

  cast_x_kernel<<<(M_ * DIM_ / 4) / 256, 256, 0, stream>>>(x, xb);
  trig_kernel<<<(N_ * DH_) / 256, 256, 0, stream>>>(pos, cT, sT);
  transpose_w_kernel<<<dim3(32, 32, 4), dim3(32, 8), 0, stream>>>(
      Wq, Wk, Wv, Wo,
      WT, WT + (size_t)DIM_ * DIM_, WT + (size_t)2 * DIM_ * DIM_, WoT);
  gemm_bt_kernel<<<dim3(QKVN / 128, M_ / 128), 256, 0, stream>>>(
      xb, WT, qkvf, nullptr, M_, QKVN, DIM_);
  rope_kernel<<<(M_ * H_ * 32) / 256, 256, 0, stream>>>(qkvf, cT, sT, qb, kb, vb);
  attn_kernel<<<(B_ * H_) * (N_ / 64), 256, 0, stream>>>(qb, kb, vb, ctx);
  gemm_bt_kernel<<<dim3(DIM_ / 128, M_ / 128), 256, 0, stream>>>(
      ctx, WoT, out, bo, M_, DIM_, DIM_);
}

// Round 2
// 226.563 us; speedup vs baseline: 1.5734x; 1.5734x over previous
//
#include <hip/hip_runtime.h>

#define B_   2
#define N_   2048
#define DIM_ 1024
#define H_   16
#define DH_  64
#define M_   (B_*N_)      // 4096 rows of x
#define QKVN (3*DIM_)     // 3072

typedef __attribute__((ext_vector_type(8)))  short short8;
typedef __attribute__((ext_vector_type(4)))  float floatx4;
typedef __attribute__((ext_vector_type(16))) float floatx16;

// ---------- helpers ----------
__device__ inline unsigned short f2b(float f) {
  union { float f; unsigned u; } v; v.f = f;
  unsigned r = v.u + 0x7fffu + ((v.u >> 16) & 1u);   // RTNE
  return (unsigned short)(r >> 16);
}

__device__ inline unsigned cvtpk(float a, float b) {  // pack 2 f32 -> 2 bf16
  unsigned d;
  asm("v_cvt_pk_bf16_f32 %0, %1, %2" : "=v"(d) : "v"(a), "v"(b));
  return d;
}

__device__ inline floatx4 mfma16(short8 a, short8 b, floatx4 c) {
  return __builtin_amdgcn_mfma_f32_16x16x32_bf16(a, b, c, 0, 0, 0);
}
__device__ inline floatx16 mfma32(short8 a, short8 b, floatx16 c) {
  return __builtin_amdgcn_mfma_f32_32x32x16_bf16(a, b, c, 0, 0, 0);
}

// XOR swizzle for [64][64] bf16 LDS tiles (128B rows): permute 16B chunks by row&7.
__device__ inline int swz(int row, int byteoff) {
  return row * 64 + (((byteoff) ^ ((row & 7) << 4)) >> 1);
}

__device__ inline void gl_lds16(const void* g, void* l) {  // 16B global -> LDS direct
  __builtin_amdgcn_global_load_lds((const __attribute__((address_space(1))) void*)g,
                                   (__attribute__((address_space(3))) void*)l, 16, 0, 0);
}

__device__ inline short8 u4_to_s8(unsigned a, unsigned b, unsigned c, unsigned d) {
  union { unsigned u[4]; short8 s; } v;
  v.u[0] = a; v.u[1] = b; v.u[2] = c; v.u[3] = d;
  return v.s;
}

// ---------- tiny prep kernels ----------
__global__ void cast_x_kernel(const float* __restrict__ x, unsigned short* __restrict__ xb) {
  int i = blockIdx.x * 256 + threadIdx.x;
  float4 v = ((const float4*)x)[i];
  ushort4 o;
  o.x = f2b(v.x); o.y = f2b(v.y); o.z = f2b(v.z); o.w = f2b(v.w);
  ((ushort4*)xb)[i] = o;
}

__global__ void trig_kernel(const float* __restrict__ pos,
                            float* __restrict__ c, float* __restrict__ s) {
  int i = blockIdx.x * 256 + threadIdx.x;
  float a = pos[i];
  c[i] = cosf(a);
  s[i] = sinf(a);
}

__global__ void transpose_w_kernel(const float* __restrict__ W0, const float* __restrict__ W1,
                                   const float* __restrict__ W2, const float* __restrict__ W3,
                                   unsigned short* __restrict__ T0, unsigned short* __restrict__ T1,
                                   unsigned short* __restrict__ T2, unsigned short* __restrict__ T3) {
  int z = blockIdx.z;
  const float* W = (z == 0) ? W0 : (z == 1) ? W1 : (z == 2) ? W2 : W3;
  unsigned short* T = (z == 0) ? T0 : (z == 1) ? T1 : (z == 2) ? T2 : T3;
  __shared__ float tile[32][33];
  int x = threadIdx.x, y = threadIdx.y;
  int bx = blockIdx.x * 32, by = blockIdx.y * 32;
  #pragma unroll
  for (int i = 0; i < 32; i += 8)
    tile[y + i][x] = W[(size_t)(by + y + i) * 1024 + bx + x];
  __syncthreads();
  #pragma unroll
  for (int i = 0; i < 32; i += 8)
    T[(size_t)(bx + y + i) * 1024 + by + x] = f2b(tile[x][y + i]);
}

// ---------- GEMM (m97 structure): C[M][N](+bias) = A_bf16[M][K] * BT_bf16[N][K] ----------
// 128x128 tile, BK=32, 4 waves (2x2), global_load_lds width-16 staging, 2 barriers/K-step.
__global__ __launch_bounds__(256) void gemm_bt_kernel(
    const unsigned short* __restrict__ A, const unsigned short* __restrict__ BT,
    float* __restrict__ C, const float* __restrict__ bias, int M, int N, int K)
{
  __shared__ __align__(16) unsigned short As[128 * 32];
  __shared__ __align__(16) unsigned short Bs[128 * 32];
  int t = threadIdx.x;
  int lane = t & 63, wave = t >> 6;
  int wr = (wave >> 1) * 64, wc = (wave & 1) * 64;

  const unsigned short* Ab = A  + (size_t)(blockIdx.y * 128) * K;
  const unsigned short* Bb = BT + (size_t)(blockIdx.x * 128) * K;

  // staging: wave w owns 1KB segments {2w, 2w+1} of each tile; lane i -> LDS seg+16*i
  int sA = wave * 2;
  int grow = (lane >> 2), gcol = (lane & 3) * 8;
  const unsigned short* ga0 = Ab + (size_t)(sA * 16 + 16 + grow) * 0; // (dummy to keep order)
  const unsigned short* gA0 = Ab + (size_t)((sA    ) * 16 + grow) * K + gcol;
  const unsigned short* gA1 = Ab + (size_t)((sA + 1) * 16 + grow) * K + gcol;
  const unsigned short* gB0 = Bb + (size_t)((sA    ) * 16 + grow) * K + gcol;
  const unsigned short* gB1 = Bb + (size_t)((sA + 1) * 16 + grow) * K + gcol;
  unsigned short* lA0 = &As[(sA    ) * 512];
  unsigned short* lA1 = &As[(sA + 1) * 512];
  unsigned short* lB0 = &Bs[(sA    ) * 512];
  unsigned short* lB1 = &Bs[(sA + 1) * 512];
  (void)ga0;

  floatx4 acc[4][4];
  #pragma unroll
  for (int i = 0; i < 4; ++i)
    #pragma unroll
    for (int j = 0; j < 4; ++j)
      acc[i][j] = (floatx4){0.f, 0.f, 0.f, 0.f};

  int nk = K >> 5;
  for (int kt = 0; kt < nk; ++kt) {
    if (kt) __syncthreads();
    int ko = kt * 32;
    gl_lds16(gA0 + ko, lA0);
    gl_lds16(gA1 + ko, lA1);
    gl_lds16(gB0 + ko, lB0);
    gl_lds16(gB1 + ko, lB1);
    __syncthreads();              // compiler drains vmcnt(0) before s_barrier
    short8 af[4], bf[4];
    #pragma unroll
    for (int fi = 0; fi < 4; ++fi)
      af[fi] = *(const short8*)&As[(wr + fi * 16 + (lane & 15)) * 32 + (lane >> 4) * 8];
    #pragma unroll
    for (int fj = 0; fj < 4; ++fj)
      bf[fj] = *(const short8*)&Bs[(wc + fj * 16 + (lane & 15)) * 32 + (lane >> 4) * 8];
    __builtin_amdgcn_s_setprio(1);
    #pragma unroll
    for (int fi = 0; fi < 4; ++fi)
      #pragma unroll
      for (int fj = 0; fj < 4; ++fj)
        acc[fi][fj] = mfma16(af[fi], bf[fj], acc[fi][fj]);
    __builtin_amdgcn_s_setprio(0);
  }

  int row0 = blockIdx.y * 128 + wr + (lane >> 4) * 4;
  int col0 = blockIdx.x * 128 + wc + (lane & 15);
  #pragma unroll
  for (int fi = 0; fi < 4; ++fi) {
    #pragma unroll
    for (int fj = 0; fj < 4; ++fj) {
      int col = col0 + fj * 16;
      float bv = bias ? bias[col] : 0.f;
      #pragma unroll
      for (int r = 0; r < 4; ++r) {
        int row = row0 + fi * 16 + r;
        C[(size_t)row * N + col] = acc[fi][fj][r] + bv;
      }
    }
  }
}

// ---------- RoPE (q,k only): qkv_f32[4096][3072] -> q,k bf16 [B*H][N][64] ----------
// q additionally scaled by DH^-0.5 * log2(e)  (softmax uses exp2)
__global__ void rope_kernel(const float* __restrict__ qkv,
                            const float* __restrict__ cT, const float* __restrict__ sT,
                            unsigned short* __restrict__ qb, unsigned short* __restrict__ kb)
{
  int tid = blockIdx.x * 256 + threadIdx.x;   // M_*H_*32 threads
  int d = tid & 31;
  int h = (tid >> 5) & 15;
  int m = tid >> 9;                            // b*N_+n
  int n = m & (N_ - 1);
  const float* rowp = qkv + (size_t)m * QKVN + h * 64 + d;
  float q1 = rowp[0],    q2 = rowp[32];
  float k1 = rowp[1024], k2 = rowp[1024 + 32];
  float c1 = cT[n * 64 + d], c2 = cT[n * 64 + d + 32];
  float s1 = sT[n * 64 + d], s2 = sT[n * 64 + d + 32];
  const float qs = 0.125f * 1.44269504088896340736f;
  size_t o = (((size_t)(m >> 11) * H_ + h) * N_ + n) * DH_ + d;
  qb[o]      = f2b((q1 * c1 - q2 * s1) * qs);
  qb[o + 32] = f2b((q2 * c2 + q1 * s2) * qs);
  kb[o]      = f2b(k1 * c1 - k2 * s1);
  kb[o + 32] = f2b(k2 * c2 + k1 * s2);
}

// ---------- V transpose: qkv v-part f32 -> vt bf16 [B*H][64 d][2048 n] ----------
__global__ void vtrans_kernel(const float* __restrict__ qkv, unsigned short* __restrict__ vt) {
  __shared__ unsigned short tile[64][72];
  int t = threadIdx.x;
  int bh = blockIdx.y;
  int n0 = blockIdx.x * 64;
  int b = bh >> 4, h = bh & 15;
  int nrow = t >> 2, d0 = (t & 3) * 16;
  const float* src = qkv + (size_t)(b * N_ + n0 + nrow) * QKVN + 2048 + h * 64 + d0;
  #pragma unroll
  for (int j = 0; j < 4; ++j) {
    float4 v = *(const float4*)(src + j * 4);
    tile[d0 + j * 4 + 0][nrow] = f2b(v.x);
    tile[d0 + j * 4 + 1][nrow] = f2b(v.y);
    tile[d0 + j * 4 + 2][nrow] = f2b(v.z);
    tile[d0 + j * 4 + 3][nrow] = f2b(v.w);
  }
  __syncthreads();
  int d = t >> 2, c0 = (t & 3) * 16;
  unsigned short* dst = vt + ((size_t)bh * 64 + d) * (size_t)N_ + n0 + c0;
  *(int4*)dst       = *(const int4*)&tile[d][c0];
  *(int4*)(dst + 8) = *(const int4*)&tile[d][c0 + 8];
}

// ---------- causal flash attention, swapped-operand 32x32 MFMA ----------
// block = 4 waves; wave owns 32 q-rows (QB=128/block); KV tile = 64, double-buffered.
// S^T = mfma(K, Q): lane owns one q-row (col) -> in-register softmax (1 shfl_xor(32)).
// O^T = mfma(V^T, P^T): alpha-rescale lane-uniform.
__global__ __launch_bounds__(256) void attn_kernel(
    const unsigned short* __restrict__ qg, const unsigned short* __restrict__ kg,
    const unsigned short* __restrict__ vtg, unsigned short* __restrict__ ctx)
{
  __shared__ __align__(16) unsigned short KV[4][4096];  // [0..1]=K dbuf, [2..3]=Vt dbuf

  int bid = blockIdx.x;
  int bh  = bid & 31;            // consecutive bids spread bh across XCDs; same bh%8 -> same XCD
  int qc  = 15 - (bid >> 5);     // big chunks dispatched first
  int q0  = qc * 128;
  int nt  = (qc + 1) * 2;

  int t = threadIdx.x, lane = t & 63, wave = t >> 6;
  int lane31 = lane & 31, hi = lane >> 5;
  int qw0 = q0 + wave * 32;
  int qr  = qw0 + lane31;        // this lane's q row

  const unsigned short* qp = qg  + ((size_t)bh * N_ + q0) * DH_;
  const unsigned short* kp = kg  + (size_t)bh * N_ * DH_;
  const unsigned short* vp = vtg + (size_t)bh * 64 * (size_t)N_;

  // ---- stage Q (128 rows x 64) into KV[0..1], swizzled ----
  {
    int r = t >> 1, bo = (t & 1) * 64;
    const unsigned short* src = qp + (size_t)r * 64;
    #pragma unroll
    for (int c = 0; c < 4; ++c) {
      int4 v = *(const int4*)(src + ((bo + c * 16) >> 1));
      *(int4*)&KV[r >> 6][swz(r & 63, bo + c * 16)] = v;
    }
  }
  __syncthreads();
  short8 qf[4];
  {
    int rb = (qw0 - q0);                 // 0..96, row within block
    int r  = rb + lane31;
    #pragma unroll
    for (int ks = 0; ks < 4; ++ks)
      qf[ks] = *(const short8*)&KV[r >> 6][swz(r & 63, ks * 32 + hi * 16)];
  }
  __syncthreads();

  // ---- staging helpers ----
  int srow = t >> 2;                 // 0..63
  int scol = (t & 3) * 16;           // element offset (2 x int4 = 32 elements? no: 16 elems x2)
  int4 kreg0, kreg1, vreg0, vreg1;

#define LOAD_TILE(KV0) do {                                                    \
    kreg0 = *(const int4*)(kp + (size_t)((KV0) + srow) * 64 + scol);           \
    kreg1 = *(const int4*)(kp + (size_t)((KV0) + srow) * 64 + scol + 8);       \
    vreg0 = *(const int4*)(vp + (size_t)srow * N_ + (KV0) + scol);             \
    vreg1 = *(const int4*)(vp + (size_t)srow * N_ + (KV0) + scol + 8);         \
  } while (0)
#define STORE_TILE(BUF) do {                                                   \
    *(int4*)&KV[(BUF)][swz(srow, (t & 3) * 32)]          = kreg0;              \
    *(int4*)&KV[(BUF)][swz(srow, (t & 3) * 32 + 16)]     = kreg1;              \
    *(int4*)&KV[2 + (BUF)][swz(srow, (t & 3) * 32)]      = vreg0;              \
    *(int4*)&KV[2 + (BUF)][swz(srow, (t & 3) * 32 + 16)] = vreg1;              \
  } while (0)

  LOAD_TILE(0);
  STORE_TILE(0);

  floatx16 oa0 = (floatx16)(0.f), oa1 = (floatx16)(0.f);
  float mr = -3.0e38f, lr = 0.f;

  for (int kt = 0; kt < nt; ++kt) {
    __syncthreads();                       // buf[kt&1] visible; buf[(kt+1)&1] free
    int kv0 = kt * 64;
    bool more = (kt + 1 < nt);
    if (more) LOAD_TILE(kv0 + 64);         // global loads in flight over compute

    bool active = (kv0 <= qw0 + 31);
    if (active) {
      const unsigned short* Kb = KV[kt & 1];
      const unsigned short* Vb = KV[2 + (kt & 1)];

      // ---- S^T = K . Q^T ----
      floatx16 sa0 = (floatx16)(0.f), sa1 = (floatx16)(0.f);
      __builtin_amdgcn_s_setprio(1);
      #pragma unroll
      for (int ks = 0; ks < 4; ++ks) {
        int bo = ks * 32 + hi * 16;
        short8 kf0 = *(const short8*)&Kb[swz(lane31, bo)];
        short8 kf1 = *(const short8*)&Kb[swz(32 + lane31, bo)];
        sa0 = mfma32(kf0, qf[ks], sa0);
        sa1 = mfma32(kf1, qf[ks], sa1);
      }
      __builtin_amdgcn_s_setprio(0);

      // ---- causal mask (diagonal tiles only) ----
      if (kv0 + 63 > qw0) {
        #pragma unroll
        for (int r = 0; r < 16; ++r) {
          int kvA = kv0 + ((r & 3) + 8 * (r >> 2) + 4 * hi);
          if (kvA > qr)      sa0[r] = -1.0e30f;
          if (kvA + 32 > qr) sa1[r] = -1.0e30f;
        }
      }

      // ---- online softmax (lane owns one q row; pair lane^32 holds other half) ----
      float pm = -3.0e38f;
      #pragma unroll
      for (int r = 0; r < 16; ++r) { pm = fmaxf(pm, sa0[r]); pm = fmaxf(pm, sa1[r]); }
      pm = fmaxf(pm, __shfl_xor(pm, 32));
      float nm = fmaxf(mr, pm);
      float al = exp2f(mr - nm);
      mr = nm;
      float ps = 0.f;
      #pragma unroll
      for (int r = 0; r < 16; ++r) {
        float p0 = exp2f(sa0[r] - nm); sa0[r] = p0; ps += p0;
        float p1 = exp2f(sa1[r] - nm); sa1[r] = p1; ps += p1;
      }
      ps += __shfl_xor(ps, 32);
      lr = lr * al + ps;
      #pragma unroll
      for (int r = 0; r < 16; ++r) { oa0[r] *= al; oa1[r] *= al; }

      // ---- pack P -> bf16, exchange halves with lane^32, PV ----
      bool hib = (hi != 0);
      #pragma unroll
      for (int kvb = 0; kvb < 2; ++kvb) {
        floatx16 sv = (kvb == 0) ? sa0 : sa1;
        unsigned pk0 = cvtpk(sv[0],  sv[1]),  pk1 = cvtpk(sv[2],  sv[3]);
        unsigned pk2 = cvtpk(sv[4],  sv[5]),  pk3 = cvtpk(sv[6],  sv[7]);
        unsigned pk4 = cvtpk(sv[8],  sv[9]),  pk5 = cvtpk(sv[10], sv[11]);
        unsigned pk6 = cvtpk(sv[12], sv[13]), pk7 = cvtpk(sv[14], sv[15]);
        unsigned t0 = hib ? pk0 : pk2, t1 = hib ? pk1 : pk3;
        unsigned t2 = hib ? pk4 : pk6, t3 = hib ? pk5 : pk7;
        unsigned r0 = (unsigned)__shfl_xor((int)t0, 32);
        unsigned r1 = (unsigned)__shfl_xor((int)t1, 32);
        unsigned r2 = (unsigned)__shfl_xor((int)t2, 32);
        unsigned r3 = (unsigned)__shfl_xor((int)t3, 32);
        unsigned o0 = hib ? pk2 : pk0, o1 = hib ? pk3 : pk1;
        unsigned o2 = hib ? pk6 : pk4, o3 = hib ? pk7 : pk5;
        short8 pa = u4_to_s8(hib ? r0 : o0, hib ? r1 : o1, hib ? o0 : r0, hib ? o1 : r1);
        short8 pb = u4_to_s8(hib ? r2 : o2, hib ? r3 : o3, hib ? o2 : r2, hib ? o3 : r3);
        int ksA = kvb * 2, ksB = kvb * 2 + 1;
        short8 v00 = *(const short8*)&Vb[swz(lane31,      ksA * 32 + hi * 16)];
        short8 v01 = *(const short8*)&Vb[swz(32 + lane31, ksA * 32 + hi * 16)];
        short8 v10 = *(const short8*)&Vb[swz(lane31,      ksB * 32 + hi * 16)];
        short8 v11 = *(const short8*)&Vb[swz(32 + lane31, ksB * 32 + hi * 16)];
        __builtin_amdgcn_s_setprio(1);
        oa0 = mfma32(v00, pa, oa0);
        oa1 = mfma32(v01, pa, oa1);
        oa0 = mfma32(v10, pb, oa0);
        oa1 = mfma32(v11, pb, oa1);
        __builtin_amdgcn_s_setprio(0);
      }
    }

    if (more) STORE_TILE((kt + 1) & 1);
  }

  // ---- epilogue: O^T (lane-local) -> LDS transpose -> coalesced ctx write ----
  __syncthreads();                       // all K/V reads done, reuse KV[0..1]
  {
    float inv = 1.0f / lr;
    int qrow = wave * 32 + lane31;       // 0..127 within block
    #pragma unroll
    for (int db = 0; db < 2; ++db) {
      floatx16 ov = (db == 0) ? oa0 : oa1;
      #pragma unroll
      for (int a = 0; a < 4; ++a) {
        unsigned w0 = cvtpk(ov[4 * a + 0] * inv, ov[4 * a + 1] * inv);
        unsigned w1 = cvtpk(ov[4 * a + 2] * inv, ov[4 * a + 3] * inv);
        int byteoff = 64 * db + 16 * a + 8 * hi;
        uint2 val; val.x = w0; val.y = w1;
        *(uint2*)&KV[qrow >> 6][(qrow & 63) * 64 + ((byteoff ^ ((qrow & 7) << 4)) >> 1)] = val;
      }
    }
  }
  __syncthreads();
  {
    int b = bh >> 4, h = bh & 15;
    int r = t >> 1, halfo = (t & 1) * 64;
    const unsigned short* srow_ = &KV[r >> 6][(r & 63) * 64];
    unsigned short* dst = ctx + (size_t)(b * N_ + q0 + r) * DIM_ + h * 64 + (halfo >> 1);
    #pragma unroll
    for (int c = 0; c < 4; ++c) {
      int byteo = halfo + c * 16;
      int4 v = *(const int4*)&srow_[(byteo ^ ((r & 7) << 4)) >> 1];
      *(int4*)(dst + c * 8) = v;
    }
  }
#undef LOAD_TILE
#undef STORE_TILE
}

// ---------- launch ----------
extern "C" void kernel_launch(void* const* d_in, const int* in_sizes, int n_in,
                              void* d_out, int out_size, void* d_ws, size_t ws_size,
                              hipStream_t stream)
{
  const float* x   = (const float*)d_in[0];
  const float* pos = (const float*)d_in[1];
  const float* Wq  = (const float*)d_in[2];
  const float* Wk  = (const float*)d_in[3];
  const float* Wv  = (const float*)d_in[4];
  const float* Wo  = (const float*)d_in[5];
  const float* bo  = (const float*)d_in[6];
  float* out = (float*)d_out;

  char* w = (char*)d_ws;
  size_t off = 0;
  auto alloc = [&](size_t bytes) {
    char* p = w + off;
    off += (bytes + 255) & ~(size_t)255;
    return p;
  };
  unsigned short* xb  = (unsigned short*)alloc((size_t)M_ * DIM_ * 2);
  unsigned short* WT  = (unsigned short*)alloc((size_t)QKVN * DIM_ * 2);
  unsigned short* WoT = (unsigned short*)alloc((size_t)DIM_ * DIM_ * 2);
  float* cT = (float*)alloc((size_t)N_ * DH_ * 4);
  float* sT = (float*)alloc((size_t)N_ * DH_ * 4);
  float* qkvf = (float*)alloc((size_t)M_ * QKVN * 4);
  unsigned short* qb  = (unsigned short*)alloc((size_t)B_ * H_ * N_ * DH_ * 2);
  unsigned short* kb  = (unsigned short*)alloc((size_t)B_ * H_ * N_ * DH_ * 2);
  unsigned short* vtb = (unsigned short*)alloc((size_t)B_ * H_ * N_ * DH_ * 2);
  unsigned short* ctx = (unsigned short*)qkvf;  // qkv_f32 dead after rope/vtrans

  cast_x_kernel<<<(M_ * DIM_ / 4) / 256, 256, 0, stream>>>(x, xb);
  trig_kernel<<<(N_ * DH_) / 256, 256, 0, stream>>>(pos, cT, sT);
  transpose_w_kernel<<<dim3(32, 32, 4), dim3(32, 8), 0, stream>>>(
      Wq, Wk, Wv, Wo,
      WT, WT + (size_t)DIM_ * DIM_, WT + (size_t)2 * DIM_ * DIM_, WoT);
  gemm_bt_kernel<<<dim3(QKVN / 128, M_ / 128), 256, 0, stream>>>(
      xb, WT, qkvf, nullptr, M_, QKVN, DIM_);
  rope_kernel<<<(M_ * H_ * 32) / 256, 256, 0, stream>>>(qkvf, cT, sT, qb, kb);
  vtrans_kernel<<<dim3(N_ / 64, B_ * H_), 256, 0, stream>>>(qkvf, vtb);
  attn_kernel<<<(B_ * H_) * (N_ / 128), 256, 0, stream>>>(qb, kb, vtb, ctx);
  gemm_bt_kernel<<<dim3(DIM_ / 128, M_ / 128), 256, 0, stream>>>(
      ctx, WoT, out, bo, M_, DIM_, DIM_);
}